// Round 1
// baseline (647.623 us; speedup 1.0000x reference)
//
#include <hip/hip_runtime.h>
#include <math.h>

#define BB 4
#define CC 96
#define NP 4096          // 64*64
#define NHEADS 6
#define DHD 16
#define NELEMF 393216.0f // C*H*W per batch
#define EPSF 1e-5f

// ---- workspace layout (float offsets) ----
#define WS_STATS 0
#define WS_W1T   64                    // mlp_w1^T  (96 x 384)
#define WS_W2T   (WS_W1T + 36864)     // mlp_w2^T  (384 x 96)
#define WS_M2A1T (WS_W2T + 36864)     // m2a_w1^T  (96 x 96)
#define WS_M2A2T (WS_M2A1T + 9216)    // m2a_w2^T  (96 x 96)
#define WS_PA1T  (WS_M2A2T + 9216)    // pa_w1^T   (96 x 12)
#define WS_Q     (WS_PA1T + 1152 + 32)
#define WS_K     (WS_Q + 1572864)
#define WS_V     (WS_K + 1572864)
#define WS_ATT   (WS_V + 1572864)
#define WS_X1    (WS_ATT + 1572864)   // hidden buffer reuses WS_Q..WS_X1
#define WS_X2    (WS_X1 + 1572864)
#define WS_X3    (WS_X2 + 1572864)
#define WS_YBN   (WS_X3 + 1572864)
#define WS_PAB   (WS_YBN + 1572864)
#define WS_GAP   (WS_PAB + 16384)
#define WS_CA    (WS_GAP + 384)

__device__ __forceinline__ float gelu_f(float x){
  return 0.5f * x * (1.0f + erff(x * 0.7071067811865476f));
}
__device__ __forceinline__ float sigmoid_f(float x){
  return 1.0f / (1.0f + __expf(-x));
}
__device__ __forceinline__ void get_ms(const float* st, int b, float& mean, float& inv, float& stdv){
  float s = st[b], s2 = st[4+b];
  mean = s * (1.0f/NELEMF);
  float var = fmaxf(s2 * (1.0f/NELEMF) - mean*mean, 0.0f);
  stdv = sqrtf(var + EPSF);
  inv = 1.0f / stdv;
}

// ---- per-batch sum/sumsq ----
__global__ void stats_kernel(const float* __restrict__ src, float* __restrict__ st){
  int b = blockIdx.x / CC, c = blockIdx.x % CC;
  const float* p = src + (b*CC + c)*NP;
  float s = 0.f, s2 = 0.f;
  for(int i = threadIdx.x; i < NP; i += 256){ float v = p[i]; s += v; s2 = fmaf(v, v, s2); }
  for(int off = 32; off > 0; off >>= 1){ s += __shfl_down(s, off); s2 += __shfl_down(s2, off); }
  __shared__ float ls[8];
  int wid = threadIdx.x >> 6;
  if((threadIdx.x & 63) == 0){ ls[wid] = s; ls[4+wid] = s2; }
  __syncthreads();
  if(threadIdx.x == 0){
    atomicAdd(&st[b],   ls[0]+ls[1]+ls[2]+ls[3]);
    atomicAdd(&st[4+b], ls[4]+ls[5]+ls[6]+ls[7]);
  }
}

// ---- transpose small weights into ws ----
__global__ void prep_weights(const float* __restrict__ w1, const float* __restrict__ w2,
                             const float* __restrict__ a1, const float* __restrict__ a2,
                             const float* __restrict__ pw1, float* __restrict__ ws){
  int gid = blockIdx.x*256 + threadIdx.x;
  if(gid < 36864){ int r = gid/96, c = gid%96; ws[WS_W1T + c*384 + r] = w1[gid]; }
  else if(gid < 73728){ int g = gid-36864; int r = g/384, c = g%384; ws[WS_W2T + c*96 + r] = w2[g]; }
  else if(gid < 82944){ int g = gid-73728; int r = g/96, c = g%96; ws[WS_M2A1T + c*96 + r] = a1[g]; }
  else if(gid < 92160){ int g = gid-82944; int r = g/96, c = g%96; ws[WS_M2A2T + c*96 + r] = a2[g]; }
  else if(gid < 93312){ int g = gid-92160; int r = g/96, c = g%96; ws[WS_PA1T + c*12 + r] = pw1[g]; }
}

// ---- fused LN + QKV projection; writes q,k,v as [b,head,pix,16] ----
__global__ void ln_qkv_kernel(const float* __restrict__ src, const float* __restrict__ st,
                              const float* __restrict__ lnw, const float* __restrict__ lnb,
                              const float* __restrict__ qw, const float* __restrict__ qbias,
                              float* __restrict__ qo, float* __restrict__ ko, float* __restrict__ vo){
  int blk = blockIdx.x; int hf = blk & 1; blk >>= 1;
  int b = blk >> 6, x = blk & 63;
  float mean, inv, stdv; get_ms(st, b, mean, inv, stdv);
  __shared__ float y[CC*64];
  for(int idx = threadIdx.x; idx < CC*64; idx += 256){
    int c = idx >> 6, p = idx & 63;
    float v = src[((b*CC + c)*64 + x)*64 + p];
    y[idx] = (v - mean)*inv*lnw[c] + lnb[c];
  }
  __syncthreads();
  int p = threadIdx.x & 63, r = threadIdx.x >> 6;
  for(int it = 0; it < 9; ++it){
    int qidx = r + 4*(it + 9*hf);
    int o = qidx*4;
    float4 acc = *(const float4*)(qbias + o);
    #pragma unroll 8
    for(int c = 0; c < CC; ++c){
      float yv = y[c*64 + p];
      float4 w = *(const float4*)(qw + c*288 + o);
      acc.x = fmaf(yv, w.x, acc.x); acc.y = fmaf(yv, w.y, acc.y);
      acc.z = fmaf(yv, w.z, acc.z); acc.w = fmaf(yv, w.w, acc.w);
    }
    int t = o / 96, head = (o % 96) >> 4, d = o & 15;
    float* dst = (t == 0) ? qo : (t == 1) ? ko : vo;
    if(t == 0){ acc.x *= 0.25f; acc.y *= 0.25f; acc.z *= 0.25f; acc.w *= 0.25f; }
    *(float4*)(dst + ((b*NHEADS + head)*NP + x*64 + p)*16 + d) = acc;
  }
}

__device__ __forceinline__ float dot16(float4 a0, float4 a1, float4 a2, float4 a3, const float4* kp){
  float4 k0 = kp[0], k1 = kp[1], k2 = kp[2], k3 = kp[3];
  float s = a0.x*k0.x;
  s = fmaf(a0.y,k0.y,s); s = fmaf(a0.z,k0.z,s); s = fmaf(a0.w,k0.w,s);
  s = fmaf(a1.x,k1.x,s); s = fmaf(a1.y,k1.y,s); s = fmaf(a1.z,k1.z,s); s = fmaf(a1.w,k1.w,s);
  s = fmaf(a2.x,k2.x,s); s = fmaf(a2.y,k2.y,s); s = fmaf(a2.z,k2.z,s); s = fmaf(a2.w,k2.w,s);
  s = fmaf(a3.x,k3.x,s); s = fmaf(a3.y,k3.y,s); s = fmaf(a3.z,k3.z,s); s = fmaf(a3.w,k3.w,s);
  return s;
}

// ---- neighborhood attention: one thread per (b,head,x,y) ----
template<int K, int D, int RPB>
__global__ void attn_kernel(const float* __restrict__ qb, const float* __restrict__ kb,
                            const float* __restrict__ vb, const float* __restrict__ rpb,
                            float* __restrict__ outp){
  int id = blockIdx.x*256 + threadIdx.x;
  int y = id & 63, x = (id >> 6) & 63;
  int bh = id >> 12;
  int head = bh % NHEADS, b = bh / NHEADS;
  const float4* qp = (const float4*)(qb + id*16);
  float4 q0 = qp[0], q1 = qp[1], q2 = qp[2], q3 = qp[3];

  int gx = x % D, px = x / D;
  int Lgx = (64 - gx + D - 1) / D;
  int sx = min(max(px - K/2, 0), Lgx - K);
  int gy = y % D, py = y / D;
  int Lgy = (64 - gy + D - 1) / D;
  int sy = min(max(py - K/2, 0), Lgy - K);

  float sc[K*K];
  float mx = -1e30f;
  int kbase = bh * NP * 16;
  #pragma unroll
  for(int i = 0; i < K; ++i){
    int hh = gx + D*(sx + i);
    const float* brow = rpb + (head*RPB + (sx + i - px + (K-1)))*RPB + (sy - py + (K-1));
    #pragma unroll
    for(int j = 0; j < K; ++j){
      int ww = gy + D*(sy + j);
      float dv = dot16(q0,q1,q2,q3, (const float4*)(kb + kbase + (hh*64 + ww)*16));
      float val = dv + brow[j];
      sc[i*K + j] = val; mx = fmaxf(mx, val);
    }
  }
  float sum = 0.f;
  #pragma unroll
  for(int n = 0; n < K*K; ++n){ float e = __expf(sc[n] - mx); sc[n] = e; sum += e; }
  float rs = 1.0f / sum;
  float4 a0 = {0,0,0,0}, a1 = a0, a2 = a0, a3 = a0;
  #pragma unroll
  for(int i = 0; i < K; ++i){
    int hh = gx + D*(sx + i);
    #pragma unroll
    for(int j = 0; j < K; ++j){
      int ww = gy + D*(sy + j);
      float wgt = sc[i*K + j] * rs;
      const float4* vp = (const float4*)(vb + kbase + (hh*64 + ww)*16);
      float4 v0 = vp[0], v1 = vp[1], v2 = vp[2], v3 = vp[3];
      a0.x=fmaf(wgt,v0.x,a0.x); a0.y=fmaf(wgt,v0.y,a0.y); a0.z=fmaf(wgt,v0.z,a0.z); a0.w=fmaf(wgt,v0.w,a0.w);
      a1.x=fmaf(wgt,v1.x,a1.x); a1.y=fmaf(wgt,v1.y,a1.y); a1.z=fmaf(wgt,v1.z,a1.z); a1.w=fmaf(wgt,v1.w,a1.w);
      a2.x=fmaf(wgt,v2.x,a2.x); a2.y=fmaf(wgt,v2.y,a2.y); a2.z=fmaf(wgt,v2.z,a2.z); a2.w=fmaf(wgt,v2.w,a2.w);
      a3.x=fmaf(wgt,v3.x,a3.x); a3.y=fmaf(wgt,v3.y,a3.y); a3.z=fmaf(wgt,v3.z,a3.z); a3.w=fmaf(wgt,v3.w,a3.w);
    }
  }
  int pix = id & 4095;
  float4* op = (float4*)(outp + (b*NP + pix)*96 + head*16);
  op[0] = a0; op[1] = a1; op[2] = a2; op[3] = a3;
}

// ---- proj + residual: x_next = sc + (att @ W + b)*rs + rb ----
__global__ void proj_res_kernel(const float* __restrict__ att, const float* __restrict__ pw,
                                const float* __restrict__ pb, const float* __restrict__ scx,
                                const float* __restrict__ st,
                                const float* __restrict__ m1w, const float* __restrict__ m1b,
                                const float* __restrict__ m2w, const float* __restrict__ m2b,
                                float* __restrict__ dst){
  int blk = blockIdx.x; int hf = blk & 1; blk >>= 1;
  int b = blk >> 6, x = blk & 63;
  float mean, inv, stdv; get_ms(st, b, mean, inv, stdv);
  __shared__ float t[64*97];
  const float* arow = att + (b*NP + x*64)*96;
  for(int i = threadIdx.x; i < 6144; i += 256) t[i + i/96] = arow[i];
  __syncthreads();
  int p = threadIdx.x & 63, r = threadIdx.x >> 6;
  for(int it = 0; it < 3; ++it){
    int q = r + 4*(it + 3*hf);
    int c4 = q*4;
    float4 acc = {0,0,0,0};
    #pragma unroll 8
    for(int co = 0; co < 96; ++co){
      float av = t[p*97 + co];
      float4 w = *(const float4*)(pw + co*96 + c4);
      acc.x = fmaf(av,w.x,acc.x); acc.y = fmaf(av,w.y,acc.y);
      acc.z = fmaf(av,w.z,acc.z); acc.w = fmaf(av,w.w,acc.w);
    }
    int base = ((b*CC + c4)*64 + x)*64 + p;
    float av[4] = {acc.x, acc.y, acc.z, acc.w};
    #pragma unroll
    for(int cc = 0; cc < 4; ++cc){
      int c = c4 + cc;
      float rsf = fmaf(m1w[c], stdv, m1b[c]);
      float rbf = fmaf(m2w[c], mean, m2b[c]);
      int a = base + cc*4096;
      dst[a] = scx[a] + (av[cc] + pb[c])*rsf + rbf;
    }
  }
}

// ---- LN + MLP first layer (relu), hidden layout [b,h,pix] ----
__global__ void mlp_hidden_kernel(const float* __restrict__ src, const float* __restrict__ st,
                                  const float* __restrict__ lnw, const float* __restrict__ lnb,
                                  const float* __restrict__ w1t, const float* __restrict__ b1,
                                  float* __restrict__ hid){
  int blk = blockIdx.x; int hf = blk & 1; blk >>= 1;
  int b = blk >> 6, x = blk & 63;
  float mean, inv, stdv; get_ms(st, b, mean, inv, stdv);
  __shared__ float y[CC*64];
  for(int idx = threadIdx.x; idx < CC*64; idx += 256){
    int c = idx >> 6, p = idx & 63;
    float v = src[((b*CC + c)*64 + x)*64 + p];
    y[idx] = (v - mean)*inv*lnw[c] + lnb[c];
  }
  __syncthreads();
  int p = threadIdx.x & 63, r = threadIdx.x >> 6;
  for(int it = 0; it < 12; ++it){
    int hq = r + 4*(it + 12*hf);
    int h4 = hq*4;
    float4 acc = *(const float4*)(b1 + h4);
    #pragma unroll 8
    for(int c = 0; c < CC; ++c){
      float yv = y[c*64 + p];
      float4 w = *(const float4*)(w1t + c*384 + h4);
      acc.x = fmaf(yv,w.x,acc.x); acc.y = fmaf(yv,w.y,acc.y);
      acc.z = fmaf(yv,w.z,acc.z); acc.w = fmaf(yv,w.w,acc.w);
    }
    acc.x = fmaxf(acc.x,0.f); acc.y = fmaxf(acc.y,0.f); acc.z = fmaxf(acc.z,0.f); acc.w = fmaxf(acc.w,0.f);
    int base = (b*384 + h4)*NP + x*64 + p;
    hid[base] = acc.x; hid[base+NP] = acc.y; hid[base+2*NP] = acc.z; hid[base+3*NP] = acc.w;
  }
}

// ---- MLP second layer + residual (sc = x1, stats of x2) ----
__global__ void mlp_out_kernel(const float* __restrict__ hid, const float* __restrict__ w2t,
                               const float* __restrict__ b2, const float* __restrict__ scx,
                               const float* __restrict__ st,
                               const float* __restrict__ m1w, const float* __restrict__ m1b,
                               const float* __restrict__ m2w, const float* __restrict__ m2b,
                               float* __restrict__ dst){
  int blk = blockIdx.x; int hf = blk & 1; blk >>= 1;
  int b = blk >> 6, x = blk & 63;
  float mean, inv, stdv; get_ms(st, b, mean, inv, stdv);
  __shared__ float hl[96*64];
  int p = threadIdx.x & 63, r = threadIdx.x >> 6;
  float4 acc[3];
  acc[0] = make_float4(0,0,0,0); acc[1] = acc[0]; acc[2] = acc[0];
  for(int chunk = 0; chunk < 4; ++chunk){
    __syncthreads();
    for(int idx = threadIdx.x; idx < 96*64; idx += 256){
      int h = idx >> 6, pp = idx & 63;
      hl[idx] = hid[(b*384 + chunk*96 + h)*NP + x*64 + pp];
    }
    __syncthreads();
    #pragma unroll 4
    for(int h = 0; h < 96; ++h){
      float hv = hl[h*64 + p];
      #pragma unroll
      for(int qq = 0; qq < 3; ++qq){
        int c4 = (r + 4*(qq + 3*hf))*4;
        float4 w = *(const float4*)(w2t + (chunk*96 + h)*96 + c4);
        acc[qq].x = fmaf(hv,w.x,acc[qq].x); acc[qq].y = fmaf(hv,w.y,acc[qq].y);
        acc[qq].z = fmaf(hv,w.z,acc[qq].z); acc[qq].w = fmaf(hv,w.w,acc[qq].w);
      }
    }
  }
  #pragma unroll
  for(int qq = 0; qq < 3; ++qq){
    int c4 = (r + 4*(qq + 3*hf))*4;
    float av[4] = {acc[qq].x, acc[qq].y, acc[qq].z, acc[qq].w};
    int base = ((b*CC + c4)*64 + x)*64 + p;
    #pragma unroll
    for(int cc = 0; cc < 4; ++cc){
      int c = c4 + cc;
      float rsf = fmaf(m1w[c], stdv, m1b[c]);
      float rbf = fmaf(m2w[c], mean, m2b[c]);
      int a = base + cc*4096;
      dst[a] = scx[a] + (av[cc] + b2[c])*rsf + rbf;
    }
  }
}

// ---- BN (inference) elementwise ----
__global__ void bn_kernel(const float* __restrict__ x3, const float* __restrict__ g,
                          const float* __restrict__ bb, const float* __restrict__ m,
                          const float* __restrict__ v, float* __restrict__ ybn){
  int idx = blockIdx.x*256 + threadIdx.x;
  int c = (idx >> 12) % CC;
  float iv = rsqrtf(v[c] + EPSF) * g[c];
  ybn[idx] = (x3[idx] - m[c])*iv + bb[c];
}

// ---- pixel attention scalar map ----
__global__ void pa_kernel(const float* __restrict__ ybn, const float* __restrict__ w1t,
                          const float* __restrict__ b1, const float* __restrict__ w2,
                          const float* __restrict__ b2, float* __restrict__ pa){
  int gid = blockIdx.x*256 + threadIdx.x;
  int b = gid >> 12, pix = gid & 4095;
  float acc[12];
  #pragma unroll
  for(int h = 0; h < 12; ++h) acc[h] = b1[h];
  for(int c = 0; c < CC; ++c){
    float yv = ybn[(b*CC + c)*NP + pix];
    #pragma unroll
    for(int h = 0; h < 12; ++h) acc[h] = fmaf(yv, w1t[c*12 + h], acc[h]);
  }
  float s = b2[0];
  #pragma unroll
  for(int h = 0; h < 12; ++h) s = fmaf(gelu_f(acc[h]), w2[h], s);
  pa[gid] = sigmoid_f(s);
}

// ---- global average pool of pa*ybn ----
__global__ void gap_kernel(const float* __restrict__ ybn, const float* __restrict__ pa,
                           float* __restrict__ gap){
  int b = blockIdx.x / CC, c = blockIdx.x % CC;
  float s = 0.f;
  for(int i = threadIdx.x; i < NP; i += 256) s = fmaf(ybn[(b*CC + c)*NP + i], pa[b*NP + i], s);
  for(int off = 32; off > 0; off >>= 1) s += __shfl_down(s, off);
  __shared__ float ls[4];
  if((threadIdx.x & 63) == 0) ls[threadIdx.x >> 6] = s;
  __syncthreads();
  if(threadIdx.x == 0) gap[blockIdx.x] = (ls[0]+ls[1]+ls[2]+ls[3]) * (1.0f/4096.0f);
}

// ---- channel attention ----
__global__ void ca_kernel(const float* __restrict__ gap, const float* __restrict__ w1,
                          const float* __restrict__ b1, const float* __restrict__ w2,
                          const float* __restrict__ b2, float* __restrict__ ca){
  int b = blockIdx.x; int o = threadIdx.x;
  __shared__ float g[96], t[96];
  if(o < 96) g[o] = gap[b*96 + o];
  __syncthreads();
  if(o < 96){
    float a = b1[o];
    for(int c = 0; c < 96; ++c) a = fmaf(g[c], w1[o*96 + c], a);
    t[o] = gelu_f(a);
  }
  __syncthreads();
  if(o < 96){
    float a = b2[o];
    for(int c = 0; c < 96; ++c) a = fmaf(t[c], w2[o*96 + c], a);
    ca[b*96 + o] = sigmoid_f(a);
  }
}

// ---- m2a double 1x1 conv + final residual ----
__global__ void m2a_final_kernel(const float* __restrict__ ybn, const float* __restrict__ pa,
                                 const float* __restrict__ ca, const float* __restrict__ w1t,
                                 const float* __restrict__ b1, const float* __restrict__ w2t,
                                 const float* __restrict__ b2, const float* __restrict__ scx,
                                 float* __restrict__ outp){
  int blk = blockIdx.x; int b = blk >> 6, x = blk & 63;
  __shared__ float y3[96*64];
  __shared__ float tl[96*64];
  for(int idx = threadIdx.x; idx < 96*64; idx += 256){
    int c = idx >> 6, p = idx & 63;
    y3[idx] = ca[b*96 + c] * pa[b*NP + x*64 + p] * ybn[(b*CC + c)*NP + x*64 + p];
  }
  __syncthreads();
  int p = threadIdx.x & 63, r = threadIdx.x >> 6;
  for(int it = 0; it < 6; ++it){
    int o4 = (r + 4*it)*4;
    float4 acc = *(const float4*)(b1 + o4);
    #pragma unroll 8
    for(int c = 0; c < 96; ++c){
      float yv = y3[c*64 + p];
      float4 w = *(const float4*)(w1t + c*96 + o4);
      acc.x = fmaf(yv,w.x,acc.x); acc.y = fmaf(yv,w.y,acc.y);
      acc.z = fmaf(yv,w.z,acc.z); acc.w = fmaf(yv,w.w,acc.w);
    }
    tl[(o4+0)*64 + p] = gelu_f(acc.x);
    tl[(o4+1)*64 + p] = gelu_f(acc.y);
    tl[(o4+2)*64 + p] = gelu_f(acc.z);
    tl[(o4+3)*64 + p] = gelu_f(acc.w);
  }
  __syncthreads();
  for(int it = 0; it < 6; ++it){
    int o4 = (r + 4*it)*4;
    float4 acc = *(const float4*)(b2 + o4);
    #pragma unroll 8
    for(int c = 0; c < 96; ++c){
      float tv = tl[c*64 + p];
      float4 w = *(const float4*)(w2t + c*96 + o4);
      acc.x = fmaf(tv,w.x,acc.x); acc.y = fmaf(tv,w.y,acc.y);
      acc.z = fmaf(tv,w.z,acc.z); acc.w = fmaf(tv,w.w,acc.w);
    }
    int base = ((b*CC + o4)*64 + x)*64 + p;
    float av[4] = {acc.x, acc.y, acc.z, acc.w};
    #pragma unroll
    for(int cc = 0; cc < 4; ++cc){
      int a = base + cc*4096;
      outp[a] = scx[a] + av[cc];
    }
  }
}

extern "C" void kernel_launch(void* const* d_in, const int* in_sizes, int n_in,
                              void* d_out, int out_size, void* d_ws, size_t ws_size,
                              hipStream_t stream){
  (void)in_sizes; (void)n_in; (void)out_size; (void)ws_size;
  const float* x     = (const float*)d_in[0];
  const float* lnw   = (const float*)d_in[1];
  const float* lnb   = (const float*)d_in[2];
  const float* m1w   = (const float*)d_in[3];
  const float* m1b   = (const float*)d_in[4];
  const float* m2w   = (const float*)d_in[5];
  const float* m2b   = (const float*)d_in[6];
  const float* qkv1w = (const float*)d_in[7];
  const float* qkv1b = (const float*)d_in[8];
  const float* proj1w= (const float*)d_in[9];
  const float* proj1b= (const float*)d_in[10];
  const float* rpb1  = (const float*)d_in[11];
  const float* qkv2w = (const float*)d_in[12];
  const float* qkv2b = (const float*)d_in[13];
  const float* proj2w= (const float*)d_in[14];
  const float* proj2b= (const float*)d_in[15];
  const float* rpb2  = (const float*)d_in[16];
  const float* mw1   = (const float*)d_in[17];
  const float* mb1   = (const float*)d_in[18];
  const float* mw2   = (const float*)d_in[19];
  const float* mb2   = (const float*)d_in[20];
  const float* bng   = (const float*)d_in[21];
  const float* bnb   = (const float*)d_in[22];
  const float* bnm   = (const float*)d_in[23];
  const float* bnv   = (const float*)d_in[24];
  const float* paw1  = (const float*)d_in[25];
  const float* pab1  = (const float*)d_in[26];
  const float* paw2  = (const float*)d_in[27];
  const float* pab2  = (const float*)d_in[28];
  const float* caw1  = (const float*)d_in[29];
  const float* cab1  = (const float*)d_in[30];
  const float* caw2  = (const float*)d_in[31];
  const float* cab2  = (const float*)d_in[32];
  const float* aw1   = (const float*)d_in[33];
  const float* ab1   = (const float*)d_in[34];
  const float* aw2   = (const float*)d_in[35];
  const float* ab2   = (const float*)d_in[36];

  float* ws  = (float*)d_ws;
  float* out = (float*)d_out;
  float* st0 = ws + WS_STATS;
  float* st1 = st0 + 8;
  float* st2 = st0 + 16;
  float* q   = ws + WS_Q;
  float* k   = ws + WS_K;
  float* v   = ws + WS_V;
  float* att = ws + WS_ATT;
  float* hid = ws + WS_Q;     // reuses q/k/v/att region (exactly 6.29M floats)
  float* x1  = ws + WS_X1;
  float* x2  = ws + WS_X2;
  float* x3  = ws + WS_X3;
  float* ybn = ws + WS_YBN;
  float* pab = ws + WS_PAB;
  float* gpb = ws + WS_GAP;
  float* cab = ws + WS_CA;

  hipMemsetAsync(d_ws, 0, 64*sizeof(float), stream);
  prep_weights<<<365, 256, 0, stream>>>(mw1, mw2, aw1, aw2, paw1, ws);

  // stage 1: attn k=7 d=1
  stats_kernel<<<384, 256, 0, stream>>>(x, st0);
  ln_qkv_kernel<<<512, 256, 0, stream>>>(x, st0, lnw, lnb, qkv1w, qkv1b, q, k, v);
  attn_kernel<7,1,13><<<384, 256, 0, stream>>>(q, k, v, rpb1, att);
  proj_res_kernel<<<512, 256, 0, stream>>>(att, proj1w, proj1b, x, st0, m1w, m1b, m2w, m2b, x1);

  // stage 2: attn k=5 d=8
  stats_kernel<<<384, 256, 0, stream>>>(x1, st1);
  ln_qkv_kernel<<<512, 256, 0, stream>>>(x1, st1, lnw, lnb, qkv2w, qkv2b, q, k, v);
  attn_kernel<5,8,9><<<384, 256, 0, stream>>>(q, k, v, rpb2, att);
  proj_res_kernel<<<512, 256, 0, stream>>>(att, proj2w, proj2b, x1, st1, m1w, m1b, m2w, m2b, x2);

  // stage 3: MLP (sc = x1 per reference!)
  stats_kernel<<<384, 256, 0, stream>>>(x2, st2);
  mlp_hidden_kernel<<<512, 256, 0, stream>>>(x2, st2, lnw, lnb, ws + WS_W1T, mb1, hid);
  mlp_out_kernel<<<512, 256, 0, stream>>>(hid, ws + WS_W2T, mb2, x1, st2, m1w, m1b, m2w, m2b, x3);

  // stage 4: BN + pixel/channel attention + m2a + final residual (sc = x3)
  bn_kernel<<<6144, 256, 0, stream>>>(x3, bng, bnb, bnm, bnv, ybn);
  pa_kernel<<<64, 256, 0, stream>>>(ybn, ws + WS_PA1T, pab1, paw2, pab2, pab);
  gap_kernel<<<384, 256, 0, stream>>>(ybn, pab, gpb);
  ca_kernel<<<4, 128, 0, stream>>>(gpb, caw1, cab1, caw2, cab2, cab);
  m2a_final_kernel<<<256, 256, 0, stream>>>(ybn, pab, cab, ws + WS_M2A1T, ab1, ws + WS_M2A2T, ab2, x3, out);
}

// Round 2
// 475.497 us; speedup vs baseline: 1.3620x; 1.3620x over previous
//
#include <hip/hip_runtime.h>
#include <math.h>

#define CC 96
#define NP 4096          // 64*64
#define NHEADS 6
#define NELEMF 393216.0f // C*H*W per batch
#define EPSF 1e-5f

// ---- workspace layout (float offsets) ----
#define WS_STATS 0
#define WS_W1T   64                    // mlp_w1^T  (96 x 384)
#define WS_W2T   (WS_W1T + 36864)      // mlp_w2^T  (384 x 96)
#define WS_M2A1T (WS_W2T + 36864)      // m2a_w1^T  (96 x 96)
#define WS_M2A2T (WS_M2A1T + 9216)     // m2a_w2^T  (96 x 96)
#define WS_PA1T  (WS_M2A2T + 9216)     // pa_w1^T   (96 x 12)
#define WS_Q     (WS_PA1T + 1152 + 32)
#define WS_K     (WS_Q + 1572864)
#define WS_V     (WS_K + 1572864)
#define WS_ATT   (WS_V + 1572864)
#define WS_X1    (WS_ATT + 1572864)    // hid reuses WS_Q..WS_X1 (4 x 1572864)
#define WS_X2    (WS_X1 + 1572864)
#define WS_X3    (WS_X2 + 1572864)
#define WS_YBN   (WS_X3 + 1572864)     // also used for LN'd y in stages 1-3
#define WS_PAB   (WS_YBN + 1572864)
#define WS_GAP   (WS_PAB + 16384)
#define WS_CA    (WS_GAP + 384)
// y3 reuses WS_Q, m2a intermediate reuses WS_K (hid dead by stage 4)

__device__ __forceinline__ float gelu_f(float x){
  return 0.5f * x * (1.0f + erff(x * 0.7071067811865476f));
}
__device__ __forceinline__ float sigmoid_f(float x){
  return 1.0f / (1.0f + __expf(-x));
}
__device__ __forceinline__ void get_ms(const float* st, int b, float& mean, float& inv, float& stdv){
  float s = st[b], s2 = st[4+b];
  mean = s * (1.0f/NELEMF);
  float var = fmaxf(s2 * (1.0f/NELEMF) - mean*mean, 0.0f);
  stdv = sqrtf(var + EPSF);
  inv = 1.0f / stdv;
}

// ---- per-batch sum/sumsq ----
__global__ void stats_kernel(const float* __restrict__ src, float* __restrict__ st){
  int b = blockIdx.x / CC, c = blockIdx.x % CC;
  const float* p = src + (b*CC + c)*NP;
  float s = 0.f, s2 = 0.f;
  for(int i = threadIdx.x; i < NP; i += 256){ float v = p[i]; s += v; s2 = fmaf(v, v, s2); }
  for(int off = 32; off > 0; off >>= 1){ s += __shfl_down(s, off); s2 += __shfl_down(s2, off); }
  __shared__ float ls[8];
  int wid = threadIdx.x >> 6;
  if((threadIdx.x & 63) == 0){ ls[wid] = s; ls[4+wid] = s2; }
  __syncthreads();
  if(threadIdx.x == 0){
    atomicAdd(&st[b],   ls[0]+ls[1]+ls[2]+ls[3]);
    atomicAdd(&st[4+b], ls[4]+ls[5]+ls[6]+ls[7]);
  }
}

// ---- transpose small weights into ws ----
__global__ void prep_weights(const float* __restrict__ w1, const float* __restrict__ w2,
                             const float* __restrict__ a1, const float* __restrict__ a2,
                             const float* __restrict__ pw1, float* __restrict__ ws){
  int gid = blockIdx.x*256 + threadIdx.x;
  if(gid < 36864){ int r = gid/96, c = gid%96; ws[WS_W1T + c*384 + r] = w1[gid]; }
  else if(gid < 73728){ int g = gid-36864; int r = g/384, c = g%384; ws[WS_W2T + c*96 + r] = w2[g]; }
  else if(gid < 82944){ int g = gid-73728; int r = g/96, c = g%96; ws[WS_M2A1T + c*96 + r] = a1[g]; }
  else if(gid < 92160){ int g = gid-82944; int r = g/96, c = g%96; ws[WS_M2A2T + c*96 + r] = a2[g]; }
  else if(gid < 93312){ int g = gid-92160; int r = g/96, c = g%96; ws[WS_PA1T + c*12 + r] = pw1[g]; }
}

// ---- LN elementwise, c-major float4 ----
__global__ void ln_kernel(const float* __restrict__ x, const float* __restrict__ st,
                          const float* __restrict__ lnw, const float* __restrict__ lnb,
                          float* __restrict__ y){
  int i4 = (blockIdx.x*256 + threadIdx.x)*4;
  int bc = i4 >> 12;
  int c = bc % CC, b = bc / CC;
  float mean, inv, stdv; get_ms(st, b, mean, inv, stdv);
  float s = inv * lnw[c];
  float o = lnb[c] - mean * s;
  float4 v = *(const float4*)(x + i4);
  v.x = fmaf(v.x, s, o); v.y = fmaf(v.y, s, o); v.z = fmaf(v.z, s, o); v.w = fmaf(v.w, s, o);
  *(float4*)(y + i4) = v;
}

// ---- GEMM core: 1 pixel/lane, 16 output channels, weights wave-uniform (s_load) ----
template<int K, int N>
__device__ __forceinline__ void gemm16(const float* __restrict__ act, const float* __restrict__ w,
                                       int n0, float4* acc){
  acc[0] = make_float4(0,0,0,0); acc[1] = acc[0]; acc[2] = acc[0]; acc[3] = acc[0];
  #pragma unroll 8
  for(int c = 0; c < K; ++c){
    float a = act[c*NP];
    #pragma unroll
    for(int j = 0; j < 4; ++j){
      float4 wv = *(const float4*)(w + c*N + n0 + j*4);
      acc[j].x = fmaf(a, wv.x, acc[j].x); acc[j].y = fmaf(a, wv.y, acc[j].y);
      acc[j].z = fmaf(a, wv.z, acc[j].z); acc[j].w = fmaf(a, wv.w, acc[j].w);
    }
  }
}

// ---- QKV projection: y[b][96][4096] x qw[96][288] -> q/k/v [b,head,pix,16] ----
__global__ void __launch_bounds__(256) gemm_qkv_kernel(
    const float* __restrict__ y, const float* __restrict__ qw, const float* __restrict__ qb,
    float* __restrict__ qo, float* __restrict__ ko, float* __restrict__ vo){
  int b = blockIdx.x >> 4, pix = (blockIdx.x & 15)*256 + threadIdx.x;
  int n0 = blockIdx.y * 16;
  float4 acc[4];
  gemm16<96,288>(y + b*CC*NP + pix, qw, n0, acc);
  int t = n0 / 96, rr = n0 % 96, head = rr >> 4;
  float scale = (t == 0) ? 0.25f : 1.0f;
  float* dst = (t == 0) ? qo : (t == 1) ? ko : vo;
  float4* op = (float4*)(dst + ((b*NHEADS + head)*NP + pix)*16);
  #pragma unroll
  for(int j = 0; j < 4; ++j){
    float4 bias = *(const float4*)(qb + n0 + j*4);
    float4 r;
    r.x = (acc[j].x + bias.x)*scale; r.y = (acc[j].y + bias.y)*scale;
    r.z = (acc[j].z + bias.z)*scale; r.w = (acc[j].w + bias.w)*scale;
    op[j] = r;
  }
}

__device__ __forceinline__ float dot16(float4 a0, float4 a1, float4 a2, float4 a3, const float4* kp){
  float4 k0 = kp[0], k1 = kp[1], k2 = kp[2], k3 = kp[3];
  float s = a0.x*k0.x;
  s = fmaf(a0.y,k0.y,s); s = fmaf(a0.z,k0.z,s); s = fmaf(a0.w,k0.w,s);
  s = fmaf(a1.x,k1.x,s); s = fmaf(a1.y,k1.y,s); s = fmaf(a1.z,k1.z,s); s = fmaf(a1.w,k1.w,s);
  s = fmaf(a2.x,k2.x,s); s = fmaf(a2.y,k2.y,s); s = fmaf(a2.z,k2.z,s); s = fmaf(a2.w,k2.w,s);
  s = fmaf(a3.x,k3.x,s); s = fmaf(a3.y,k3.y,s); s = fmaf(a3.z,k3.z,s); s = fmaf(a3.w,k3.w,s);
  return s;
}

// ---- neighborhood attention: one thread per (b,head,x,y); output c-major via LDS ----
template<int K, int D, int RPB>
__global__ void attn_kernel(const float* __restrict__ qb, const float* __restrict__ kb,
                            const float* __restrict__ vb, const float* __restrict__ rpb,
                            float* __restrict__ outp){
  int id = blockIdx.x*256 + threadIdx.x;
  int y = id & 63, x = (id >> 6) & 63;
  int bh = id >> 12;
  int head = bh % NHEADS, b = bh / NHEADS;
  const float4* qp = (const float4*)(qb + id*16);
  float4 q0 = qp[0], q1 = qp[1], q2 = qp[2], q3 = qp[3];

  int gx = x % D, px = x / D;
  int Lgx = (64 - gx + D - 1) / D;
  int sx = min(max(px - K/2, 0), Lgx - K);
  int gy = y % D, py = y / D;
  int Lgy = (64 - gy + D - 1) / D;
  int sy = min(max(py - K/2, 0), Lgy - K);

  float sc[K*K];
  float mx = -1e30f;
  int kbase = bh * NP * 16;
  #pragma unroll
  for(int i = 0; i < K; ++i){
    int hh = gx + D*(sx + i);
    const float* brow = rpb + (head*RPB + (sx + i - px + (K-1)))*RPB + (sy - py + (K-1));
    #pragma unroll
    for(int j = 0; j < K; ++j){
      int ww = gy + D*(sy + j);
      float dv = dot16(q0,q1,q2,q3, (const float4*)(kb + kbase + (hh*64 + ww)*16));
      float val = dv + brow[j];
      sc[i*K + j] = val; mx = fmaxf(mx, val);
    }
  }
  float sum = 0.f;
  #pragma unroll
  for(int n = 0; n < K*K; ++n){ float e = __expf(sc[n] - mx); sc[n] = e; sum += e; }
  float rs = 1.0f / sum;
  float4 a0 = {0,0,0,0}, a1 = a0, a2 = a0, a3 = a0;
  #pragma unroll
  for(int i = 0; i < K; ++i){
    int hh = gx + D*(sx + i);
    #pragma unroll
    for(int j = 0; j < K; ++j){
      int ww = gy + D*(sy + j);
      float wgt = sc[i*K + j] * rs;
      const float4* vp = (const float4*)(vb + kbase + (hh*64 + ww)*16);
      float4 v0 = vp[0], v1 = vp[1], v2 = vp[2], v3 = vp[3];
      a0.x=fmaf(wgt,v0.x,a0.x); a0.y=fmaf(wgt,v0.y,a0.y); a0.z=fmaf(wgt,v0.z,a0.z); a0.w=fmaf(wgt,v0.w,a0.w);
      a1.x=fmaf(wgt,v1.x,a1.x); a1.y=fmaf(wgt,v1.y,a1.y); a1.z=fmaf(wgt,v1.z,a1.z); a1.w=fmaf(wgt,v1.w,a1.w);
      a2.x=fmaf(wgt,v2.x,a2.x); a2.y=fmaf(wgt,v2.y,a2.y); a2.z=fmaf(wgt,v2.z,a2.z); a2.w=fmaf(wgt,v2.w,a2.w);
      a3.x=fmaf(wgt,v3.x,a3.x); a3.y=fmaf(wgt,v3.y,a3.y); a3.z=fmaf(wgt,v3.z,a3.z); a3.w=fmaf(wgt,v3.w,a3.w);
    }
  }
  // write c-major att[b][head*16+d][4096] via LDS transpose
  __shared__ float ol[16*256];
  int t = threadIdx.x;
  ol[ 0*256+t]=a0.x; ol[ 1*256+t]=a0.y; ol[ 2*256+t]=a0.z; ol[ 3*256+t]=a0.w;
  ol[ 4*256+t]=a1.x; ol[ 5*256+t]=a1.y; ol[ 6*256+t]=a1.z; ol[ 7*256+t]=a1.w;
  ol[ 8*256+t]=a2.x; ol[ 9*256+t]=a2.y; ol[10*256+t]=a2.z; ol[11*256+t]=a2.w;
  ol[12*256+t]=a3.x; ol[13*256+t]=a3.y; ol[14*256+t]=a3.z; ol[15*256+t]=a3.w;
  __syncthreads();
  int pixbase = (blockIdx.x & 15)*256;
  int cb = b*CC + head*16;
  for(int i = t; i < 4096; i += 256){
    int c = i >> 8, p = i & 255;
    outp[(cb + c)*NP + pixbase + p] = ol[c*256 + p];
  }
}

// ---- proj + residual: x_next = sc + (att @ W + pb)*rs + rb  (c-major everywhere) ----
__global__ void __launch_bounds__(256) gemm_proj_kernel(
    const float* __restrict__ att, const float* __restrict__ pw, const float* __restrict__ pb,
    const float* __restrict__ scx, const float* __restrict__ st,
    const float* __restrict__ m1w, const float* __restrict__ m1b,
    const float* __restrict__ m2w, const float* __restrict__ m2b,
    float* __restrict__ dst){
  int b = blockIdx.x >> 4, pix = (blockIdx.x & 15)*256 + threadIdx.x;
  int n0 = blockIdx.y * 16;
  float4 acc[4];
  gemm16<96,96>(att + b*CC*NP + pix, pw, n0, acc);
  float mean, inv, stdv; get_ms(st, b, mean, inv, stdv);
  const float* a = (const float*)acc;
  #pragma unroll
  for(int cc = 0; cc < 16; ++cc){
    int c = n0 + cc;
    float rsf = fmaf(m1w[c], stdv, m1b[c]);
    float rbf = fmaf(m2w[c], mean, m2b[c]);
    int ad = (b*CC + c)*NP + pix;
    dst[ad] = scx[ad] + (a[cc] + pb[c])*rsf + rbf;
  }
}

// ---- MLP layer 1: relu(y @ w1t + b1) -> hid c-major ----
__global__ void __launch_bounds__(256) gemm_mlp1_kernel(
    const float* __restrict__ y, const float* __restrict__ w1t, const float* __restrict__ b1,
    float* __restrict__ hid){
  int b = blockIdx.x >> 4, pix = (blockIdx.x & 15)*256 + threadIdx.x;
  int n0 = blockIdx.y * 16;
  float4 acc[4];
  gemm16<96,384>(y + b*CC*NP + pix, w1t, n0, acc);
  const float* a = (const float*)acc;
  #pragma unroll
  for(int cc = 0; cc < 16; ++cc){
    int h = n0 + cc;
    hid[(b*384 + h)*NP + pix] = fmaxf(a[cc] + b1[h], 0.f);
  }
}

// ---- MLP layer 2 + residual (sc = x1) ----
__global__ void __launch_bounds__(256) gemm_mlp2_kernel(
    const float* __restrict__ hid, const float* __restrict__ w2t, const float* __restrict__ b2,
    const float* __restrict__ scx, const float* __restrict__ st,
    const float* __restrict__ m1w, const float* __restrict__ m1b,
    const float* __restrict__ m2w, const float* __restrict__ m2b,
    float* __restrict__ dst){
  int b = blockIdx.x >> 4, pix = (blockIdx.x & 15)*256 + threadIdx.x;
  int n0 = blockIdx.y * 16;
  float4 acc[4];
  gemm16<384,96>(hid + b*384*NP + pix, w2t, n0, acc);
  float mean, inv, stdv; get_ms(st, b, mean, inv, stdv);
  const float* a = (const float*)acc;
  #pragma unroll
  for(int cc = 0; cc < 16; ++cc){
    int c = n0 + cc;
    float rsf = fmaf(m1w[c], stdv, m1b[c]);
    float rbf = fmaf(m2w[c], mean, m2b[c]);
    int ad = (b*CC + c)*NP + pix;
    dst[ad] = scx[ad] + (a[cc] + b2[c])*rsf + rbf;
  }
}

// ---- BN (inference) elementwise ----
__global__ void bn_kernel(const float* __restrict__ x3, const float* __restrict__ g,
                          const float* __restrict__ bb, const float* __restrict__ m,
                          const float* __restrict__ v, float* __restrict__ ybn){
  int idx = blockIdx.x*256 + threadIdx.x;
  int c = (idx >> 12) % CC;
  float iv = rsqrtf(v[c] + EPSF) * g[c];
  ybn[idx] = (x3[idx] - m[c])*iv + bb[c];
}

// ---- pixel attention scalar map: 64-thread blocks, 256 blocks ----
__global__ void __launch_bounds__(64) pa_kernel(
    const float* __restrict__ ybn, const float* __restrict__ w1t,
    const float* __restrict__ b1, const float* __restrict__ w2,
    const float* __restrict__ b2, float* __restrict__ pa){
  int pix = blockIdx.x*64 + threadIdx.x;
  int b = blockIdx.x >> 6;       // 64 blocks per batch
  int p = pix & 4095;
  float acc[12];
  #pragma unroll
  for(int h = 0; h < 12; ++h) acc[h] = b1[h];
  #pragma unroll 4
  for(int c = 0; c < CC; ++c){
    float yv = ybn[(b*CC + c)*NP + p];
    #pragma unroll
    for(int h = 0; h < 12; ++h) acc[h] = fmaf(yv, w1t[c*12 + h], acc[h]);
  }
  float s = b2[0];
  #pragma unroll
  for(int h = 0; h < 12; ++h) s = fmaf(gelu_f(acc[h]), w2[h], s);
  pa[pix] = sigmoid_f(s);
}

// ---- global average pool of pa*ybn ----
__global__ void gap_kernel(const float* __restrict__ ybn, const float* __restrict__ pa,
                           float* __restrict__ gap){
  int b = blockIdx.x / CC, c = blockIdx.x % CC;
  float s = 0.f;
  for(int i = threadIdx.x; i < NP; i += 256) s = fmaf(ybn[(b*CC + c)*NP + i], pa[b*NP + i], s);
  for(int off = 32; off > 0; off >>= 1) s += __shfl_down(s, off);
  __shared__ float ls[4];
  if((threadIdx.x & 63) == 0) ls[threadIdx.x >> 6] = s;
  __syncthreads();
  if(threadIdx.x == 0) gap[blockIdx.x] = (ls[0]+ls[1]+ls[2]+ls[3]) * (1.0f/4096.0f);
}

// ---- channel attention ----
__global__ void ca_kernel(const float* __restrict__ gap, const float* __restrict__ w1,
                          const float* __restrict__ b1, const float* __restrict__ w2,
                          const float* __restrict__ b2, float* __restrict__ ca){
  int b = blockIdx.x; int o = threadIdx.x;
  __shared__ float g[96], t[96];
  if(o < 96) g[o] = gap[b*96 + o];
  __syncthreads();
  if(o < 96){
    float a = b1[o];
    for(int c = 0; c < 96; ++c) a = fmaf(g[c], w1[o*96 + c], a);
    t[o] = gelu_f(a);
  }
  __syncthreads();
  if(o < 96){
    float a = b2[o];
    for(int c = 0; c < 96; ++c) a = fmaf(t[c], w2[o*96 + c], a);
    ca[b*96 + o] = sigmoid_f(a);
  }
}

// ---- y3 = ca * pa * ybn (c-major elementwise) ----
__global__ void y3_kernel(const float* __restrict__ ybn, const float* __restrict__ pa,
                          const float* __restrict__ ca, float* __restrict__ y3){
  int idx = blockIdx.x*256 + threadIdx.x;
  int pix = idx & 4095, bc = idx >> 12;
  int c = bc % CC, b = bc / CC;
  y3[idx] = ca[b*CC + c] * pa[b*NP + pix] * ybn[idx];
}

// ---- m2a layer 1: gelu(y3 @ w1t + b1) ----
__global__ void __launch_bounds__(256) gemm_m2a1_kernel(
    const float* __restrict__ y3, const float* __restrict__ w1t, const float* __restrict__ b1,
    float* __restrict__ tb){
  int b = blockIdx.x >> 4, pix = (blockIdx.x & 15)*256 + threadIdx.x;
  int n0 = blockIdx.y * 16;
  float4 acc[4];
  gemm16<96,96>(y3 + b*CC*NP + pix, w1t, n0, acc);
  const float* a = (const float*)acc;
  #pragma unroll
  for(int cc = 0; cc < 16; ++cc){
    int c = n0 + cc;
    tb[(b*CC + c)*NP + pix] = gelu_f(a[cc] + b1[c]);
  }
}

// ---- m2a layer 2 + final residual ----
__global__ void __launch_bounds__(256) gemm_m2a2_kernel(
    const float* __restrict__ tb, const float* __restrict__ w2t, const float* __restrict__ b2,
    const float* __restrict__ scx, float* __restrict__ outp){
  int b = blockIdx.x >> 4, pix = (blockIdx.x & 15)*256 + threadIdx.x;
  int n0 = blockIdx.y * 16;
  float4 acc[4];
  gemm16<96,96>(tb + b*CC*NP + pix, w2t, n0, acc);
  const float* a = (const float*)acc;
  #pragma unroll
  for(int cc = 0; cc < 16; ++cc){
    int c = n0 + cc;
    int ad = (b*CC + c)*NP + pix;
    outp[ad] = scx[ad] + a[cc] + b2[c];
  }
}

extern "C" void kernel_launch(void* const* d_in, const int* in_sizes, int n_in,
                              void* d_out, int out_size, void* d_ws, size_t ws_size,
                              hipStream_t stream){
  (void)in_sizes; (void)n_in; (void)out_size; (void)ws_size;
  const float* x     = (const float*)d_in[0];
  const float* lnw   = (const float*)d_in[1];
  const float* lnb   = (const float*)d_in[2];
  const float* m1w   = (const float*)d_in[3];
  const float* m1b   = (const float*)d_in[4];
  const float* m2w   = (const float*)d_in[5];
  const float* m2b   = (const float*)d_in[6];
  const float* qkv1w = (const float*)d_in[7];
  const float* qkv1b = (const float*)d_in[8];
  const float* proj1w= (const float*)d_in[9];
  const float* proj1b= (const float*)d_in[10];
  const float* rpb1  = (const float*)d_in[11];
  const float* qkv2w = (const float*)d_in[12];
  const float* qkv2b = (const float*)d_in[13];
  const float* proj2w= (const float*)d_in[14];
  const float* proj2b= (const float*)d_in[15];
  const float* rpb2  = (const float*)d_in[16];
  const float* mw1   = (const float*)d_in[17];
  const float* mb1   = (const float*)d_in[18];
  const float* mw2   = (const float*)d_in[19];
  const float* mb2   = (const float*)d_in[20];
  const float* bng   = (const float*)d_in[21];
  const float* bnb   = (const float*)d_in[22];
  const float* bnm   = (const float*)d_in[23];
  const float* bnv   = (const float*)d_in[24];
  const float* paw1  = (const float*)d_in[25];
  const float* pab1  = (const float*)d_in[26];
  const float* paw2  = (const float*)d_in[27];
  const float* pab2  = (const float*)d_in[28];
  const float* caw1  = (const float*)d_in[29];
  const float* cab1  = (const float*)d_in[30];
  const float* caw2  = (const float*)d_in[31];
  const float* cab2  = (const float*)d_in[32];
  const float* aw1   = (const float*)d_in[33];
  const float* ab1   = (const float*)d_in[34];
  const float* aw2   = (const float*)d_in[35];
  const float* ab2   = (const float*)d_in[36];

  float* ws  = (float*)d_ws;
  float* out = (float*)d_out;
  float* st0 = ws + WS_STATS;
  float* st1 = st0 + 8;
  float* st2 = st0 + 16;
  float* q   = ws + WS_Q;
  float* k   = ws + WS_K;
  float* v   = ws + WS_V;
  float* att = ws + WS_ATT;
  float* hid = ws + WS_Q;      // reuses q/k/v/att region
  float* x1  = ws + WS_X1;
  float* x2  = ws + WS_X2;
  float* x3  = ws + WS_X3;
  float* yb  = ws + WS_YBN;    // LN'd y (stages 1-3) / ybn (stage 4)
  float* pab = ws + WS_PAB;
  float* gpb = ws + WS_GAP;
  float* cab = ws + WS_CA;
  float* y3  = ws + WS_Q;      // stage-4 reuse
  float* tbf = ws + WS_K;      // stage-4 reuse

  hipMemsetAsync(d_ws, 0, 64*sizeof(float), stream);
  prep_weights<<<365, 256, 0, stream>>>(mw1, mw2, aw1, aw2, paw1, ws);

  // stage 1: attn k=7 d=1
  stats_kernel<<<384, 256, 0, stream>>>(x, st0);
  ln_kernel<<<1536, 256, 0, stream>>>(x, st0, lnw, lnb, yb);
  gemm_qkv_kernel<<<dim3(64,18), 256, 0, stream>>>(yb, qkv1w, qkv1b, q, k, v);
  attn_kernel<7,1,13><<<384, 256, 0, stream>>>(q, k, v, rpb1, att);
  gemm_proj_kernel<<<dim3(64,6), 256, 0, stream>>>(att, proj1w, proj1b, x, st0, m1w, m1b, m2w, m2b, x1);

  // stage 2: attn k=5 d=8
  stats_kernel<<<384, 256, 0, stream>>>(x1, st1);
  ln_kernel<<<1536, 256, 0, stream>>>(x1, st1, lnw, lnb, yb);
  gemm_qkv_kernel<<<dim3(64,18), 256, 0, stream>>>(yb, qkv2w, qkv2b, q, k, v);
  attn_kernel<5,8,9><<<384, 256, 0, stream>>>(q, k, v, rpb2, att);
  gemm_proj_kernel<<<dim3(64,6), 256, 0, stream>>>(att, proj2w, proj2b, x1, st1, m1w, m1b, m2w, m2b, x2);

  // stage 3: MLP (sc = x1 per reference)
  stats_kernel<<<384, 256, 0, stream>>>(x2, st2);
  ln_kernel<<<1536, 256, 0, stream>>>(x2, st2, lnw, lnb, yb);
  gemm_mlp1_kernel<<<dim3(64,24), 256, 0, stream>>>(yb, ws + WS_W1T, mb1, hid);
  gemm_mlp2_kernel<<<dim3(64,6), 256, 0, stream>>>(hid, ws + WS_W2T, mb2, x1, st2, m1w, m1b, m2w, m2b, x3);

  // stage 4: BN + pixel/channel attention + m2a + final residual (sc = x3)
  bn_kernel<<<6144, 256, 0, stream>>>(x3, bng, bnb, bnm, bnv, yb);
  pa_kernel<<<256, 64, 0, stream>>>(yb, ws + WS_PA1T, pab1, paw2, pab2, pab);
  gap_kernel<<<384, 256, 0, stream>>>(yb, pab, gpb);
  ca_kernel<<<4, 128, 0, stream>>>(gpb, caw1, cab1, caw2, cab2, cab);
  y3_kernel<<<6144, 256, 0, stream>>>(yb, pab, cab, y3);
  gemm_m2a1_kernel<<<dim3(64,6), 256, 0, stream>>>(y3, ws + WS_M2A1T, ab1, tbf);
  gemm_m2a2_kernel<<<dim3(64,6), 256, 0, stream>>>(tbf, ws + WS_M2A2T, ab2, x3, out);
}

// Round 3
// 398.466 us; speedup vs baseline: 1.6253x; 1.1933x over previous
//
#include <hip/hip_runtime.h>
#include <math.h>

#define CC 96
#define NP 4096          // 64*64
#define NHEADS 6
#define NELEMF 393216.0f // C*H*W per batch
#define EPSF 1e-5f

// ---- workspace layout (float offsets) ----
#define WS_STATS 0
#define WS_W1T   64                    // mlp_w1^T  (96 x 384)
#define WS_W2T   (WS_W1T + 36864)      // mlp_w2^T  (384 x 96)
#define WS_M2A1T (WS_W2T + 36864)      // m2a_w1^T  (96 x 96)
#define WS_M2A2T (WS_M2A1T + 9216)     // m2a_w2^T  (96 x 96)
#define WS_PA1T  (WS_M2A2T + 9216)     // pa_w1^T   (96 x 12)
#define WS_Q     (WS_PA1T + 1152 + 32)
#define WS_K     (WS_Q + 1572864)
#define WS_V     (WS_K + 1572864)
#define WS_ATT   (WS_V + 1572864)
#define WS_X1    (WS_ATT + 1572864)    // hid reuses WS_Q..WS_X1 (4 x 1572864)
#define WS_X2    (WS_X1 + 1572864)
#define WS_X3    (WS_X2 + 1572864)
#define WS_YBN   (WS_X3 + 1572864)
#define WS_PAB   (WS_YBN + 1572864)
#define WS_GAP   (WS_PAB + 16384)
#define WS_CA    (WS_GAP + 384)

__device__ __forceinline__ float gelu_f(float x){
  return 0.5f * x * (1.0f + erff(x * 0.7071067811865476f));
}
__device__ __forceinline__ float sigmoid_f(float x){
  return 1.0f / (1.0f + __expf(-x));
}
__device__ __forceinline__ void get_ms(const float* st, int b, float& mean, float& inv, float& stdv){
  float s = st[b], s2 = st[4+b];
  mean = s * (1.0f/NELEMF);
  float var = fmaxf(s2 * (1.0f/NELEMF) - mean*mean, 0.0f);
  stdv = sqrtf(var + EPSF);
  inv = 1.0f / stdv;
}

// ---- per-batch sum/sumsq ----
__global__ void stats_kernel(const float* __restrict__ src, float* __restrict__ st){
  int b = blockIdx.x / CC, c = blockIdx.x % CC;
  const float* p = src + (b*CC + c)*NP;
  float s = 0.f, s2 = 0.f;
  for(int i = threadIdx.x; i < NP; i += 256){ float v = p[i]; s += v; s2 = fmaf(v, v, s2); }
  for(int off = 32; off > 0; off >>= 1){ s += __shfl_down(s, off); s2 += __shfl_down(s2, off); }
  __shared__ float ls[8];
  int wid = threadIdx.x >> 6;
  if((threadIdx.x & 63) == 0){ ls[wid] = s; ls[4+wid] = s2; }
  __syncthreads();
  if(threadIdx.x == 0){
    atomicAdd(&st[b],   ls[0]+ls[1]+ls[2]+ls[3]);
    atomicAdd(&st[4+b], ls[4]+ls[5]+ls[6]+ls[7]);
  }
}

// ---- transpose small weights into ws ----
__global__ void prep_weights(const float* __restrict__ w1, const float* __restrict__ w2,
                             const float* __restrict__ a1, const float* __restrict__ a2,
                             const float* __restrict__ pw1, float* __restrict__ ws){
  int gid = blockIdx.x*256 + threadIdx.x;
  if(gid < 36864){ int r = gid/96, c = gid%96; ws[WS_W1T + c*384 + r] = w1[gid]; }
  else if(gid < 73728){ int g = gid-36864; int r = g/384, c = g%384; ws[WS_W2T + c*96 + r] = w2[g]; }
  else if(gid < 82944){ int g = gid-73728; int r = g/96, c = g%96; ws[WS_M2A1T + c*96 + r] = a1[g]; }
  else if(gid < 92160){ int g = gid-82944; int r = g/96, c = g%96; ws[WS_M2A2T + c*96 + r] = a2[g]; }
  else if(gid < 93312){ int g = gid-92160; int r = g/96, c = g%96; ws[WS_PA1T + c*12 + r] = pw1[g]; }
}

// ---- QKV projection with fused LN: 16 outputs/thread ----
__global__ void __launch_bounds__(256) gemm_qkv_kernel(
    const float* __restrict__ xin, const float* __restrict__ st,
    const float* __restrict__ lnw, const float* __restrict__ lnb,
    const float* __restrict__ qw, const float* __restrict__ qb,
    float* __restrict__ qo, float* __restrict__ ko, float* __restrict__ vo){
  int b = blockIdx.x >> 4, pix = (blockIdx.x & 15)*256 + threadIdx.x;
  int n0 = blockIdx.y * 16;
  float mean, inv, stdv; get_ms(st, b, mean, inv, stdv);
  const float* act = xin + b*CC*NP + pix;
  float4 acc[4];
  acc[0] = make_float4(0,0,0,0); acc[1] = acc[0]; acc[2] = acc[0]; acc[3] = acc[0];
  #pragma unroll 8
  for(int c = 0; c < CC; ++c){
    float s = inv * lnw[c];
    float o = lnb[c] - mean * s;
    float a = fmaf(act[c*NP], s, o);
    #pragma unroll
    for(int j = 0; j < 4; ++j){
      float4 wv = *(const float4*)(qw + c*288 + n0 + j*4);
      acc[j].x = fmaf(a, wv.x, acc[j].x); acc[j].y = fmaf(a, wv.y, acc[j].y);
      acc[j].z = fmaf(a, wv.z, acc[j].z); acc[j].w = fmaf(a, wv.w, acc[j].w);
    }
  }
  int t = n0 / 96, rr = n0 % 96, head = rr >> 4;
  float scale = (t == 0) ? 0.25f : 1.0f;
  float* dst = (t == 0) ? qo : (t == 1) ? ko : vo;
  float4* op = (float4*)(dst + ((b*NHEADS + head)*NP + pix)*16);
  #pragma unroll
  for(int j = 0; j < 4; ++j){
    float4 bias = *(const float4*)(qb + n0 + j*4);
    float4 r;
    r.x = (acc[j].x + bias.x)*scale; r.y = (acc[j].y + bias.y)*scale;
    r.z = (acc[j].z + bias.z)*scale; r.w = (acc[j].w + bias.w)*scale;
    op[j] = r;
  }
}

// ---- neighborhood attention: 4 lanes per pixel (lane t owns dims 4t..4t+3) ----
template<int K, int D, int RPB>
__global__ void __launch_bounds__(256) attn_kernel(
    const float* __restrict__ qb, const float* __restrict__ kb,
    const float* __restrict__ vb, const float* __restrict__ rpb,
    float* __restrict__ outp){
  int bh = blockIdx.x >> 6;
  int pixbase = (blockIdx.x & 63) * 64;
  int pixoff = threadIdx.x >> 2, t = threadIdx.x & 3;
  int pix = pixbase + pixoff;
  int x = pix >> 6, y = pix & 63;
  int head = bh % NHEADS, b = bh / NHEADS;
  const float4 q = *(const float4*)(qb + (bh*NP + pix)*16 + 4*t);

  int gx = x % D, px = x / D;
  int Lgx = (64 - gx + D - 1) / D;
  int sx = min(max(px - K/2, 0), Lgx - K);
  int gy = y % D, py = y / D;
  int Lgy = (64 - gy + D - 1) / D;
  int sy = min(max(py - K/2, 0), Lgy - K);

  const float* kbp = kb + bh*NP*16 + 4*t;
  float sc[K*K];
  #pragma unroll
  for(int i = 0; i < K; ++i){
    int hh = gx + D*(sx + i);
    #pragma unroll
    for(int j = 0; j < K; ++j){
      int ww = gy + D*(sy + j);
      float4 kv = *(const float4*)(kbp + (hh*64 + ww)*16);
      float s = q.x*kv.x;
      s = fmaf(q.y, kv.y, s); s = fmaf(q.z, kv.z, s); s = fmaf(q.w, kv.w, s);
      sc[i*K + j] = s;
    }
  }
  float mx = -1e30f;
  #pragma unroll
  for(int i = 0; i < K; ++i){
    const float* brow = rpb + (head*RPB + (sx + i - px + (K-1)))*RPB + (sy - py + (K-1));
    #pragma unroll
    for(int j = 0; j < K; ++j){
      float s = sc[i*K + j];
      s += __shfl_xor(s, 1);
      s += __shfl_xor(s, 2);
      s += brow[j];
      sc[i*K + j] = s;
      mx = fmaxf(mx, s);
    }
  }
  float sum = 0.f;
  #pragma unroll
  for(int n = 0; n < K*K; ++n){ float e = __expf(sc[n] - mx); sc[n] = e; sum += e; }
  float rs = 1.0f / sum;
  const float* vbp = vb + bh*NP*16 + 4*t;
  float4 acc = {0,0,0,0};
  #pragma unroll
  for(int i = 0; i < K; ++i){
    int hh = gx + D*(sx + i);
    #pragma unroll
    for(int j = 0; j < K; ++j){
      int ww = gy + D*(sy + j);
      float wgt = sc[i*K + j] * rs;
      float4 vv = *(const float4*)(vbp + (hh*64 + ww)*16);
      acc.x = fmaf(wgt, vv.x, acc.x); acc.y = fmaf(wgt, vv.y, acc.y);
      acc.z = fmaf(wgt, vv.z, acc.z); acc.w = fmaf(wgt, vv.w, acc.w);
    }
  }
  // transpose to c-major: ol[16 c][64 pix], row stride 68 (2-way LDS aliasing only)
  __shared__ float ol[16*68];
  int r0 = 4*t;
  ol[(r0+0)*68 + pixoff] = acc.x;
  ol[(r0+1)*68 + pixoff] = acc.y;
  ol[(r0+2)*68 + pixoff] = acc.z;
  ol[(r0+3)*68 + pixoff] = acc.w;
  __syncthreads();
  int cb = b*CC + head*16;
  for(int idx = threadIdx.x; idx < 1024; idx += 256){
    int c = idx >> 6, p = idx & 63;
    outp[(cb + c)*NP + pixbase + p] = ol[c*68 + p];
  }
}

// ---- 8-output GEMM core ----
template<int K, int N>
__device__ __forceinline__ void gemm8(const float* __restrict__ act, const float* __restrict__ w,
                                      int n0, float4& a0, float4& a1){
  a0 = make_float4(0,0,0,0); a1 = a0;
  #pragma unroll 8
  for(int c = 0; c < K; ++c){
    float a = act[c*NP];
    float4 w0 = *(const float4*)(w + c*N + n0);
    float4 w1 = *(const float4*)(w + c*N + n0 + 4);
    a0.x = fmaf(a, w0.x, a0.x); a0.y = fmaf(a, w0.y, a0.y);
    a0.z = fmaf(a, w0.z, a0.z); a0.w = fmaf(a, w0.w, a0.w);
    a1.x = fmaf(a, w1.x, a1.x); a1.y = fmaf(a, w1.y, a1.y);
    a1.z = fmaf(a, w1.z, a1.z); a1.w = fmaf(a, w1.w, a1.w);
  }
}

// ---- proj + residual ----
__global__ void __launch_bounds__(256) gemm_proj_kernel(
    const float* __restrict__ att, const float* __restrict__ pw, const float* __restrict__ pb,
    const float* __restrict__ scx, const float* __restrict__ st,
    const float* __restrict__ m1w, const float* __restrict__ m1b,
    const float* __restrict__ m2w, const float* __restrict__ m2b,
    float* __restrict__ dst){
  int b = blockIdx.x >> 4, pix = (blockIdx.x & 15)*256 + threadIdx.x;
  int n0 = blockIdx.y * 8;
  float4 a0, a1;
  gemm8<96,96>(att + b*CC*NP + pix, pw, n0, a0, a1);
  float mean, inv, stdv; get_ms(st, b, mean, inv, stdv);
  float av[8] = {a0.x,a0.y,a0.z,a0.w,a1.x,a1.y,a1.z,a1.w};
  #pragma unroll
  for(int cc = 0; cc < 8; ++cc){
    int c = n0 + cc;
    float rsf = fmaf(m1w[c], stdv, m1b[c]);
    float rbf = fmaf(m2w[c], mean, m2b[c]);
    int ad = (b*CC + c)*NP + pix;
    dst[ad] = scx[ad] + (av[cc] + pb[c])*rsf + rbf;
  }
}

// ---- MLP layer 1 with fused LN: 16 outputs/thread ----
__global__ void __launch_bounds__(256) gemm_mlp1_kernel(
    const float* __restrict__ xin, const float* __restrict__ st,
    const float* __restrict__ lnw, const float* __restrict__ lnb,
    const float* __restrict__ w1t, const float* __restrict__ b1,
    float* __restrict__ hid){
  int b = blockIdx.x >> 4, pix = (blockIdx.x & 15)*256 + threadIdx.x;
  int n0 = blockIdx.y * 16;
  float mean, inv, stdv; get_ms(st, b, mean, inv, stdv);
  const float* act = xin + b*CC*NP + pix;
  float4 acc[4];
  acc[0] = make_float4(0,0,0,0); acc[1] = acc[0]; acc[2] = acc[0]; acc[3] = acc[0];
  #pragma unroll 8
  for(int c = 0; c < CC; ++c){
    float s = inv * lnw[c];
    float o = lnb[c] - mean * s;
    float a = fmaf(act[c*NP], s, o);
    #pragma unroll
    for(int j = 0; j < 4; ++j){
      float4 wv = *(const float4*)(w1t + c*384 + n0 + j*4);
      acc[j].x = fmaf(a, wv.x, acc[j].x); acc[j].y = fmaf(a, wv.y, acc[j].y);
      acc[j].z = fmaf(a, wv.z, acc[j].z); acc[j].w = fmaf(a, wv.w, acc[j].w);
    }
  }
  const float* a = (const float*)acc;
  #pragma unroll
  for(int cc = 0; cc < 16; ++cc){
    int h = n0 + cc;
    hid[(b*384 + h)*NP + pix] = fmaxf(a[cc] + b1[h], 0.f);
  }
}

// ---- MLP layer 2 + residual (sc = x1) ----
__global__ void __launch_bounds__(256) gemm_mlp2_kernel(
    const float* __restrict__ hid, const float* __restrict__ w2t, const float* __restrict__ b2,
    const float* __restrict__ scx, const float* __restrict__ st,
    const float* __restrict__ m1w, const float* __restrict__ m1b,
    const float* __restrict__ m2w, const float* __restrict__ m2b,
    float* __restrict__ dst){
  int b = blockIdx.x >> 4, pix = (blockIdx.x & 15)*256 + threadIdx.x;
  int n0 = blockIdx.y * 8;
  float4 a0, a1;
  gemm8<384,96>(hid + b*384*NP + pix, w2t, n0, a0, a1);
  float mean, inv, stdv; get_ms(st, b, mean, inv, stdv);
  float av[8] = {a0.x,a0.y,a0.z,a0.w,a1.x,a1.y,a1.z,a1.w};
  #pragma unroll
  for(int cc = 0; cc < 8; ++cc){
    int c = n0 + cc;
    float rsf = fmaf(m1w[c], stdv, m1b[c]);
    float rbf = fmaf(m2w[c], mean, m2b[c]);
    int ad = (b*CC + c)*NP + pix;
    dst[ad] = scx[ad] + (av[cc] + b2[c])*rsf + rbf;
  }
}

// ---- BN (inference) elementwise ----
__global__ void bn_kernel(const float* __restrict__ x3, const float* __restrict__ g,
                          const float* __restrict__ bb, const float* __restrict__ m,
                          const float* __restrict__ v, float* __restrict__ ybn){
  int idx = blockIdx.x*256 + threadIdx.x;
  int c = (idx >> 12) % CC;
  float iv = rsqrtf(v[c] + EPSF) * g[c];
  ybn[idx] = (x3[idx] - m[c])*iv + bb[c];
}

// ---- pixel attention scalar map ----
__global__ void __launch_bounds__(64) pa_kernel(
    const float* __restrict__ ybn, const float* __restrict__ w1t,
    const float* __restrict__ b1, const float* __restrict__ w2,
    const float* __restrict__ b2, float* __restrict__ pa){
  int pix = blockIdx.x*64 + threadIdx.x;
  int b = blockIdx.x >> 6;
  int p = pix & 4095;
  float acc[12];
  #pragma unroll
  for(int h = 0; h < 12; ++h) acc[h] = b1[h];
  #pragma unroll 4
  for(int c = 0; c < CC; ++c){
    float yv = ybn[(b*CC + c)*NP + p];
    #pragma unroll
    for(int h = 0; h < 12; ++h) acc[h] = fmaf(yv, w1t[c*12 + h], acc[h]);
  }
  float s = b2[0];
  #pragma unroll
  for(int h = 0; h < 12; ++h) s = fmaf(gelu_f(acc[h]), w2[h], s);
  pa[pix] = sigmoid_f(s);
}

// ---- global average pool of pa*ybn ----
__global__ void gap_kernel(const float* __restrict__ ybn, const float* __restrict__ pa,
                           float* __restrict__ gap){
  int b = blockIdx.x / CC, c = blockIdx.x % CC;
  float s = 0.f;
  for(int i = threadIdx.x; i < NP; i += 256) s = fmaf(ybn[(b*CC + c)*NP + i], pa[b*NP + i], s);
  for(int off = 32; off > 0; off >>= 1) s += __shfl_down(s, off);
  __shared__ float ls[4];
  if((threadIdx.x & 63) == 0) ls[threadIdx.x >> 6] = s;
  __syncthreads();
  if(threadIdx.x == 0) gap[blockIdx.x] = (ls[0]+ls[1]+ls[2]+ls[3]) * (1.0f/4096.0f);
}

// ---- channel attention ----
__global__ void ca_kernel(const float* __restrict__ gap, const float* __restrict__ w1,
                          const float* __restrict__ b1, const float* __restrict__ w2,
                          const float* __restrict__ b2, float* __restrict__ ca){
  int b = blockIdx.x; int o = threadIdx.x;
  __shared__ float g[96], t[96];
  if(o < 96) g[o] = gap[b*96 + o];
  __syncthreads();
  if(o < 96){
    float a = b1[o];
    for(int c = 0; c < 96; ++c) a = fmaf(g[c], w1[o*96 + c], a);
    t[o] = gelu_f(a);
  }
  __syncthreads();
  if(o < 96){
    float a = b2[o];
    for(int c = 0; c < 96; ++c) a = fmaf(t[c], w2[o*96 + c], a);
    ca[b*96 + o] = sigmoid_f(a);
  }
}

// ---- m2a layer 1 with fused y3 = ca*pa*ybn: gelu(y3 @ w1t + b1) ----
__global__ void __launch_bounds__(256) gemm_m2a1_kernel(
    const float* __restrict__ ybn, const float* __restrict__ pa, const float* __restrict__ ca,
    const float* __restrict__ w1t, const float* __restrict__ b1,
    float* __restrict__ tb){
  int b = blockIdx.x >> 4, pix = (blockIdx.x & 15)*256 + threadIdx.x;
  int n0 = blockIdx.y * 8;
  const float* act = ybn + b*CC*NP + pix;
  const float* cac = ca + b*CC;
  float pav = pa[b*NP + pix];
  float4 a0 = make_float4(0,0,0,0), a1 = a0;
  #pragma unroll 8
  for(int c = 0; c < CC; ++c){
    float a = act[c*NP] * (cac[c] * pav);
    float4 w0 = *(const float4*)(w1t + c*96 + n0);
    float4 w1 = *(const float4*)(w1t + c*96 + n0 + 4);
    a0.x = fmaf(a, w0.x, a0.x); a0.y = fmaf(a, w0.y, a0.y);
    a0.z = fmaf(a, w0.z, a0.z); a0.w = fmaf(a, w0.w, a0.w);
    a1.x = fmaf(a, w1.x, a1.x); a1.y = fmaf(a, w1.y, a1.y);
    a1.z = fmaf(a, w1.z, a1.z); a1.w = fmaf(a, w1.w, a1.w);
  }
  float av[8] = {a0.x,a0.y,a0.z,a0.w,a1.x,a1.y,a1.z,a1.w};
  #pragma unroll
  for(int cc = 0; cc < 8; ++cc){
    int c = n0 + cc;
    tb[(b*CC + c)*NP + pix] = gelu_f(av[cc] + b1[c]);
  }
}

// ---- m2a layer 2 + final residual ----
__global__ void __launch_bounds__(256) gemm_m2a2_kernel(
    const float* __restrict__ tb, const float* __restrict__ w2t, const float* __restrict__ b2,
    const float* __restrict__ scx, float* __restrict__ outp){
  int b = blockIdx.x >> 4, pix = (blockIdx.x & 15)*256 + threadIdx.x;
  int n0 = blockIdx.y * 8;
  float4 a0, a1;
  gemm8<96,96>(tb + b*CC*NP + pix, w2t, n0, a0, a1);
  float av[8] = {a0.x,a0.y,a0.z,a0.w,a1.x,a1.y,a1.z,a1.w};
  #pragma unroll
  for(int cc = 0; cc < 8; ++cc){
    int c = n0 + cc;
    int ad = (b*CC + c)*NP + pix;
    outp[ad] = scx[ad] + av[cc] + b2[c];
  }
}

extern "C" void kernel_launch(void* const* d_in, const int* in_sizes, int n_in,
                              void* d_out, int out_size, void* d_ws, size_t ws_size,
                              hipStream_t stream){
  (void)in_sizes; (void)n_in; (void)out_size; (void)ws_size;
  const float* x     = (const float*)d_in[0];
  const float* lnw   = (const float*)d_in[1];
  const float* lnb   = (const float*)d_in[2];
  const float* m1w   = (const float*)d_in[3];
  const float* m1b   = (const float*)d_in[4];
  const float* m2w   = (const float*)d_in[5];
  const float* m2b   = (const float*)d_in[6];
  const float* qkv1w = (const float*)d_in[7];
  const float* qkv1b = (const float*)d_in[8];
  const float* proj1w= (const float*)d_in[9];
  const float* proj1b= (const float*)d_in[10];
  const float* rpb1  = (const float*)d_in[11];
  const float* qkv2w = (const float*)d_in[12];
  const float* qkv2b = (const float*)d_in[13];
  const float* proj2w= (const float*)d_in[14];
  const float* proj2b= (const float*)d_in[15];
  const float* rpb2  = (const float*)d_in[16];
  const float* mw1   = (const float*)d_in[17];
  const float* mb1   = (const float*)d_in[18];
  const float* mw2   = (const float*)d_in[19];
  const float* mb2   = (const float*)d_in[20];
  const float* bng   = (const float*)d_in[21];
  const float* bnb   = (const float*)d_in[22];
  const float* bnm   = (const float*)d_in[23];
  const float* bnv   = (const float*)d_in[24];
  const float* paw1  = (const float*)d_in[25];
  const float* pab1  = (const float*)d_in[26];
  const float* paw2  = (const float*)d_in[27];
  const float* pab2  = (const float*)d_in[28];
  const float* caw1  = (const float*)d_in[29];
  const float* cab1  = (const float*)d_in[30];
  const float* caw2  = (const float*)d_in[31];
  const float* cab2  = (const float*)d_in[32];
  const float* aw1   = (const float*)d_in[33];
  const float* ab1   = (const float*)d_in[34];
  const float* aw2   = (const float*)d_in[35];
  const float* ab2   = (const float*)d_in[36];

  float* ws  = (float*)d_ws;
  float* out = (float*)d_out;
  float* st0 = ws + WS_STATS;
  float* st1 = st0 + 8;
  float* st2 = st0 + 16;
  float* q   = ws + WS_Q;
  float* k   = ws + WS_K;
  float* v   = ws + WS_V;
  float* att = ws + WS_ATT;
  float* hid = ws + WS_Q;
  float* x1  = ws + WS_X1;
  float* x2  = ws + WS_X2;
  float* x3  = ws + WS_X3;
  float* yb  = ws + WS_YBN;
  float* pab = ws + WS_PAB;
  float* gpb = ws + WS_GAP;
  float* cab = ws + WS_CA;
  float* tbf = ws + WS_K;

  hipMemsetAsync(d_ws, 0, 64*sizeof(float), stream);
  prep_weights<<<365, 256, 0, stream>>>(mw1, mw2, aw1, aw2, paw1, ws);

  // stage 1: attn k=7 d=1
  stats_kernel<<<384, 256, 0, stream>>>(x, st0);
  gemm_qkv_kernel<<<dim3(64,18), 256, 0, stream>>>(x, st0, lnw, lnb, qkv1w, qkv1b, q, k, v);
  attn_kernel<7,1,13><<<1536, 256, 0, stream>>>(q, k, v, rpb1, att);
  gemm_proj_kernel<<<dim3(64,12), 256, 0, stream>>>(att, proj1w, proj1b, x, st0, m1w, m1b, m2w, m2b, x1);

  // stage 2: attn k=5 d=8
  stats_kernel<<<384, 256, 0, stream>>>(x1, st1);
  gemm_qkv_kernel<<<dim3(64,18), 256, 0, stream>>>(x1, st1, lnw, lnb, qkv2w, qkv2b, q, k, v);
  attn_kernel<5,8,9><<<1536, 256, 0, stream>>>(q, k, v, rpb2, att);
  gemm_proj_kernel<<<dim3(64,12), 256, 0, stream>>>(att, proj2w, proj2b, x1, st1, m1w, m1b, m2w, m2b, x2);

  // stage 3: MLP (sc = x1 per reference)
  stats_kernel<<<384, 256, 0, stream>>>(x2, st2);
  gemm_mlp1_kernel<<<dim3(64,24), 256, 0, stream>>>(x2, st2, lnw, lnb, ws + WS_W1T, mb1, hid);
  gemm_mlp2_kernel<<<dim3(64,12), 256, 0, stream>>>(hid, ws + WS_W2T, mb2, x1, st2, m1w, m1b, m2w, m2b, x3);

  // stage 4: BN + pixel/channel attention + m2a + final residual (sc = x3)
  bn_kernel<<<6144, 256, 0, stream>>>(x3, bng, bnb, bnm, bnv, yb);
  pa_kernel<<<256, 64, 0, stream>>>(yb, ws + WS_PA1T, pab1, paw2, pab2, pab);
  gap_kernel<<<384, 256, 0, stream>>>(yb, pab, gpb);
  ca_kernel<<<4, 128, 0, stream>>>(gpb, caw1, cab1, caw2, cab2, cab);
  gemm_m2a1_kernel<<<dim3(64,12), 256, 0, stream>>>(yb, pab, cab, ws + WS_M2A1T, ab1, tbf);
  gemm_m2a2_kernel<<<dim3(64,12), 256, 0, stream>>>(tbf, ws + WS_M2A2T, ab2, x3, out);
}